// Round 2
// baseline (69.702 us; speedup 1.0000x reference)
//
#include <hip/hip_runtime.h>
#include <math.h>

// Problem geometry (fixed by the reference)
#define M_SAMPLES 256
#define IN_DIM    512
#define RDIM      513          // IN_DIM + 1 (bias row)
#define CDIM      512
#define N_ROWS    (M_SAMPLES * CDIM)   // 131072 (m,c) pairs
#define ROWS_PER_WAVE 16
#define BLOCK     256          // 4 waves per block
#define GRID      (N_ROWS / ((BLOCK / 64) * ROWS_PER_WAVE))  // 2048

// 4-byte-aligned float4 proxy: E/mu/sigma rows have odd stride 513, so row
// bases are only 4B-aligned. gfx950 supports unaligned dwordx4 loads.
struct f4a { float x, y, z, w; };

__global__ __launch_bounds__(256) void sigma_kernel(const float* __restrict__ var,
                                                    float* __restrict__ sigma,
                                                    int n) {
    int i = blockIdx.x * blockDim.x + threadIdx.x;
    if (i < n) sigma[i] = sqrtf(var[i]);
}

template <bool USE_SIGMA>
__global__ __launch_bounds__(256) void bnn_kernel(const float* __restrict__ x,
                                                  const float* __restrict__ mu,
                                                  const float* __restrict__ var,
                                                  const float* __restrict__ E,
                                                  const float* __restrict__ sigma,
                                                  float* __restrict__ out) {
    const int lane = threadIdx.x & 63;
    const int wave = blockIdx.x * (BLOCK >> 6) + (threadIdx.x >> 6);
    const int row0 = wave * ROWS_PER_WAVE;

    const int iA = lane * 4;        // elements [iA, iA+4)
    const int iB = 256 + lane * 4;  // elements [iB, iB+4)

#pragma unroll 1
    for (int row = row0; row < row0 + ROWS_PER_WAVE; ++row) {
        const int m = row >> 9;      // row / 512
        const int c = row & 511;     // row % 512
        const float* __restrict__ Er  = E  + (size_t)row * RDIM;
        const float* __restrict__ mur = mu + c * RDIM;
        const float* __restrict__ sgr = (USE_SIGMA ? sigma : var) + c * RDIM;
        const float* __restrict__ xr  = x + m * IN_DIM;

        // Vector loads (coalesced: lane i covers bytes [16i,16i+16) of each segment)
        f4a eA = *(const f4a*)(Er + iA);
        f4a eB = *(const f4a*)(Er + iB);
        f4a mA = *(const f4a*)(mur + iA);
        f4a mB = *(const f4a*)(mur + iB);
        f4a sA = *(const f4a*)(sgr + iA);
        f4a sB = *(const f4a*)(sgr + iB);
        float4 xA = *(const float4*)(xr + iA);   // x rows are 16B-aligned
        float4 xB = *(const float4*)(xr + iB);

        if (!USE_SIGMA) {
            sA.x = sqrtf(sA.x); sA.y = sqrtf(sA.y); sA.z = sqrtf(sA.z); sA.w = sqrtf(sA.w);
            sB.x = sqrtf(sB.x); sB.y = sqrtf(sB.y); sB.z = sqrtf(sB.z); sB.w = sqrtf(sB.w);
        }

        // acc = sum x * (mu + sigma*E)
        float acc;
        acc =            xA.x * fmaf(sA.x, eA.x, mA.x);
        acc = fmaf(xA.y, fmaf(sA.y, eA.y, mA.y), acc);
        acc = fmaf(xA.z, fmaf(sA.z, eA.z, mA.z), acc);
        acc = fmaf(xA.w, fmaf(sA.w, eA.w, mA.w), acc);
        acc = fmaf(xB.x, fmaf(sB.x, eB.x, mB.x), acc);
        acc = fmaf(xB.y, fmaf(sB.y, eB.y, mB.y), acc);
        acc = fmaf(xB.z, fmaf(sB.z, eB.z, mB.z), acc);
        acc = fmaf(xB.w, fmaf(sB.w, eB.w, mB.w), acc);

        // Wave-wide sum (64 lanes)
#pragma unroll
        for (int off = 32; off >= 1; off >>= 1)
            acc += __shfl_xor(acc, off, 64);

        if (lane == 0) {
            // bias element r = 512 (x_hat = 1)
            float sg = USE_SIGMA ? sgr[512] : sqrtf(sgr[512]);
            acc += fmaf(sg, Er[512], mur[512]);
            out[row] = acc;
        }
    }
}

extern "C" void kernel_launch(void* const* d_in, const int* in_sizes, int n_in,
                              void* d_out, int out_size, void* d_ws, size_t ws_size,
                              hipStream_t stream) {
    const float* x   = (const float*)d_in[0];
    const float* mu  = (const float*)d_in[1];
    const float* var = (const float*)d_in[2];
    const float* E   = (const float*)d_in[3];
    // d_in[4] = shape scalar (unused; geometry is compile-time)
    float* out = (float*)d_out;

    const size_t sigma_bytes = (size_t)CDIM * RDIM * sizeof(float);
    if (ws_size >= sigma_bytes) {
        float* sigma = (float*)d_ws;
        sigma_kernel<<<(CDIM * RDIM + BLOCK - 1) / BLOCK, BLOCK, 0, stream>>>(var, sigma, CDIM * RDIM);
        bnn_kernel<true><<<GRID, BLOCK, 0, stream>>>(x, mu, var, E, sigma, out);
    } else {
        bnn_kernel<false><<<GRID, BLOCK, 0, stream>>>(x, mu, var, E, nullptr, out);
    }
}

// Round 3
// 61.664 us; speedup vs baseline: 1.1304x; 1.1304x over previous
//
#include <hip/hip_runtime.h>
#include <math.h>

// Geometry (fixed by the reference)
#define Mdim 256
#define Cdim 512
#define Rdim 513            // IN_DIM + 1 bias row
#define SIGMA_ELEMS (Cdim * Rdim)   // 262656

__global__ __launch_bounds__(256) void sigma_kernel(const float* __restrict__ var,
                                                    float* __restrict__ sigma, int n) {
    int i = blockIdx.x * 256 + threadIdx.x;
    if (i < n) sigma[i] = sqrtf(var[i]);
}

// One wave per (m,c) row of 513 floats. Each wave owns rows with a fixed
// c mod 4 == q, so pad = (4-q)&3 is wave-constant and the element window
// [pad, pad+4*CH) of every E/sigma/mu row is exactly 16B-aligned
// (row*513 = row mod 4 = c mod 4; pad cancels it). x_hat for the window is
// wave-invariant -> kept in registers. Depth-1 prefetch of the next row's
// six float4s overlaps HBM latency with the FMA + shuffle-reduce.
template <bool USE_SIGMA>
__global__ __launch_bounds__(256) void bnn_kernel(const float* __restrict__ x,
                                                  const float* __restrict__ mu,
                                                  const float* __restrict__ sg,   // sigma (or var if !USE_SIGMA)
                                                  const float* __restrict__ E,
                                                  float* __restrict__ out) {
    const int lane = threadIdx.x & 63;
    const int q    = threadIdx.x >> 6;      // wave id == c mod 4
    const int b    = blockIdx.x;            // 2048 blocks
    const int m    = b >> 3;
    const int j    = b & 7;

    const int pad  = (4 - q) & 3;
    const int CH   = pad ? 127 : 128;       // float4 chunks in the aligned window
    const int eA   = pad + 4 * lane;                 // first chunk's element
    const int eB   = pad + 4 * (CH - 64 + lane);     // second chunk's element

    // x_hat window in registers (x rows are [m][512]; window stays < 512)
    const float* __restrict__ xr = x + m * 512;
    float xA0 = xr[eA], xA1 = xr[eA + 1], xA2 = xr[eA + 2], xA3 = xr[eA + 3];
    float xB0 = xr[eB], xB1 = xr[eB + 1], xB2 = xr[eB + 2], xB3 = xr[eB + 3];
    // CH==127: lane63's 1st chunk and lane0's 2nd chunk are both chunk 63 -> zero the dup
    if (pad && lane == 0) { xB0 = xB1 = xB2 = xB3 = 0.f; }

    // Scalar leftovers: leading [0,pad) + tail [pad+4CH, 513) (incl. bias r=512)
    const int nS = pad ? 5 : 1;
    int se = -1;
    if (lane < nS) se = (lane < pad) ? lane : (pad + 4 * CH + (lane - pad));
    const float xs = (se >= 0) ? ((se < 512) ? xr[se] : 1.0f) : 0.0f;

    int row = m * 512 + j * 64 + q;         // current (m,c) row; c advances by 4
    size_t eb = (size_t)row * (size_t)Rdim; // E element base
    size_t cb = (size_t)(j * 64 + q) * (size_t)Rdim; // mu/sigma element base

    // Current-row loads (all float4s provably 16B-aligned)
    float4 cEa = *(const float4*)(E + eb + eA);
    float4 cEb = *(const float4*)(E + eb + eB);
    float4 cSa = *(const float4*)(sg + cb + eA);
    float4 cSb = *(const float4*)(sg + cb + eB);
    float4 cMa = *(const float4*)(mu + cb + eA);
    float4 cMb = *(const float4*)(mu + cb + eB);
    float cEs = 0.f, cSs = 0.f, cMs = 0.f;
    if (se >= 0) { cEs = E[eb + se]; cSs = sg[cb + se]; cMs = mu[cb + se]; }

#pragma unroll
    for (int k = 0; k < 16; ++k) {
        // ---- prefetch next row (issued before the compute; counted vmcnt) ----
        float4 nEa, nEb, nSa, nSb, nMa, nMb;
        float  nEs = 0.f, nSs = 0.f, nMs = 0.f;
        if (k < 15) {
            const size_t eb2 = eb + 4 * (size_t)Rdim;
            const size_t cb2 = cb + 4 * (size_t)Rdim;
            nEa = *(const float4*)(E + eb2 + eA);
            nEb = *(const float4*)(E + eb2 + eB);
            nSa = *(const float4*)(sg + cb2 + eA);
            nSb = *(const float4*)(sg + cb2 + eB);
            nMa = *(const float4*)(mu + cb2 + eA);
            nMb = *(const float4*)(mu + cb2 + eB);
            if (se >= 0) { nEs = E[eb2 + se]; nSs = sg[cb2 + se]; nMs = mu[cb2 + se]; }
        }

        // ---- compute current row ----
        float4 sa = cSa, sb = cSb;
        float  ss = cSs;
        if (!USE_SIGMA) {
            sa.x = sqrtf(sa.x); sa.y = sqrtf(sa.y); sa.z = sqrtf(sa.z); sa.w = sqrtf(sa.w);
            sb.x = sqrtf(sb.x); sb.y = sqrtf(sb.y); sb.z = sqrtf(sb.z); sb.w = sqrtf(sb.w);
            ss = sqrtf(ss);
        }
        float acc;
        acc =            xA0 * fmaf(sa.x, cEa.x, cMa.x);
        acc = fmaf(xA1, fmaf(sa.y, cEa.y, cMa.y), acc);
        acc = fmaf(xA2, fmaf(sa.z, cEa.z, cMa.z), acc);
        acc = fmaf(xA3, fmaf(sa.w, cEa.w, cMa.w), acc);
        acc = fmaf(xB0, fmaf(sb.x, cEb.x, cMb.x), acc);
        acc = fmaf(xB1, fmaf(sb.y, cEb.y, cMb.y), acc);
        acc = fmaf(xB2, fmaf(sb.z, cEb.z, cMb.z), acc);
        acc = fmaf(xB3, fmaf(sb.w, cEb.w, cMb.w), acc);
        acc = fmaf(xs,  fmaf(ss, cEs, cMs), acc);   // scalar leftovers (xs==0 on idle lanes)

        // wave-wide sum (64 lanes)
#pragma unroll
        for (int off = 32; off >= 1; off >>= 1)
            acc += __shfl_xor(acc, off, 64);

        if (lane == 0) out[row] = acc;

        // ---- rotate ----
        if (k < 15) {
            cEa = nEa; cEb = nEb; cSa = nSa; cSb = nSb; cMa = nMa; cMb = nMb;
            cEs = nEs; cSs = nSs; cMs = nMs;
            eb += 4 * (size_t)Rdim;
            cb += 4 * (size_t)Rdim;
            row += 4;
        }
    }
}

extern "C" void kernel_launch(void* const* d_in, const int* in_sizes, int n_in,
                              void* d_out, int out_size, void* d_ws, size_t ws_size,
                              hipStream_t stream) {
    const float* x   = (const float*)d_in[0];
    const float* mu  = (const float*)d_in[1];
    const float* var = (const float*)d_in[2];
    const float* E   = (const float*)d_in[3];
    float* out = (float*)d_out;

    const size_t sigma_bytes = (size_t)SIGMA_ELEMS * sizeof(float);
    if (ws_size >= sigma_bytes) {
        float* sigma = (float*)d_ws;
        sigma_kernel<<<(SIGMA_ELEMS + 255) / 256, 256, 0, stream>>>(var, sigma, SIGMA_ELEMS);
        bnn_kernel<true><<<2048, 256, 0, stream>>>(x, mu, sigma, E, out);
    } else {
        bnn_kernel<false><<<2048, 256, 0, stream>>>(x, mu, var, E, out);
    }
}